// Round 6
// baseline (578.831 us; speedup 1.0000x reference)
//
#include <hip/hip_runtime.h>
#include <hip/hip_bf16.h>

typedef __attribute__((ext_vector_type(8))) short bf16x8;
typedef __attribute__((ext_vector_type(4))) float f32x4;
typedef __attribute__((ext_vector_type(16))) float f32x16;

#define DEVI static __device__ __forceinline__

constexpr int BS = 4, SEQ = 2048, DIN = 4096, DOUT = 4096, RANK = 128;
constexpr int MTOT = BS * SEQ;  // 8192

DEVI unsigned short f2bf(float f) {
  __hip_bfloat16 h = __float2bfloat16(f);
  return __builtin_bit_cast(unsigned short, h);
}

// ---------------- fused prep kernel ----------------
// One grid-stride kernel over all float4 units of: x cast, w_lin cast,
// w_out cast, m = bf16(0.01*exp(64*log_lr)*state + w_bsp).

__global__ void prep_all_kernel(const float* __restrict__ x,
                                const float* __restrict__ w_lin,
                                const float* __restrict__ w_out,
                                const float* __restrict__ log_lr,
                                const float* __restrict__ state,
                                const float* __restrict__ w_bsp,
                                unsigned short* __restrict__ xbf,
                                unsigned short* __restrict__ wlbf,
                                unsigned short* __restrict__ wobf,
                                unsigned short* __restrict__ mbf) {
  constexpr int N_X = MTOT * DIN / 4;          // 8388608
  constexpr int N_WL = DOUT * DIN / 4;         // 4194304
  constexpr int N_WO = DOUT * RANK / 4;        // 131072
  constexpr int N_M = BS * RANK * DIN / 4;     // 524288
  constexpr int O1 = N_X, O2 = O1 + N_WL, O3 = O2 + N_WO, O4 = O3 + N_M;
  int i = blockIdx.x * blockDim.x + threadIdx.x;
  int stride = gridDim.x * blockDim.x;
  for (; i < O4; i += stride) {
    if (i < O1) {
      float4 v = reinterpret_cast<const float4*>(x)[i];
      ushort4 o{f2bf(v.x), f2bf(v.y), f2bf(v.z), f2bf(v.w)};
      reinterpret_cast<ushort4*>(xbf)[i] = o;
    } else if (i < O2) {
      int j = i - O1;
      float4 v = reinterpret_cast<const float4*>(w_lin)[j];
      ushort4 o{f2bf(v.x), f2bf(v.y), f2bf(v.z), f2bf(v.w)};
      reinterpret_cast<ushort4*>(wlbf)[j] = o;
    } else if (i < O3) {
      int j = i - O2;
      float4 v = reinterpret_cast<const float4*>(w_out)[j];
      ushort4 o{f2bf(v.x), f2bf(v.y), f2bf(v.z), f2bf(v.w)};
      reinterpret_cast<ushort4*>(wobf)[j] = o;
    } else {
      int j = i - O3;
      int ri4 = j & (RANK * DIN / 4 - 1);
      float4 ll = reinterpret_cast<const float4*>(log_lr)[ri4];
      float4 wb = reinterpret_cast<const float4*>(w_bsp)[ri4];
      float4 st = reinterpret_cast<const float4*>(state)[j];
      ushort4 o;
      o.x = f2bf(0.01f * __expf(ll.x * 64.0f) * st.x + wb.x);
      o.y = f2bf(0.01f * __expf(ll.y * 64.0f) * st.y + wb.y);
      o.z = f2bf(0.01f * __expf(ll.z * 64.0f) * st.z + wb.z);
      o.w = f2bf(0.01f * __expf(ll.w * 64.0f) * st.w + wb.w);
      reinterpret_cast<ushort4*>(mbf)[j] = o;
    }
  }
}

// ---------------- shared building blocks ----------------

DEVI void gload16(const void* g, void* l) {
  __builtin_amdgcn_global_load_lds(
      (const __attribute__((address_space(1))) void*)g,
      (__attribute__((address_space(3))) void*)l, 16, 0, 0);
}

// Linear (unswizzled) staging for the small z kernel: [ROWS][32] bf16 tile.
template <int ROWS>
DEVI void stage_tile(const char* gbase, int ldBytes, char* lds) {
  const int lane = threadIdx.x & 63;
  const int wave = threadIdx.x >> 6;
  constexpr int CHUNKS = ROWS / 16;
  constexpr int CPW = CHUNKS / 4;
  const int colByte = (lane & 3) << 4;
  const int rowInChunk = lane >> 2;
#pragma unroll
  for (int c = 0; c < CPW; ++c) {
    int chunk = wave * CPW + c;
    int row = chunk * 16 + rowInChunk;
    gload16(gbase + (size_t)row * ldBytes + colByte, lds + chunk * 1024);
  }
}

template <int F>
DEVI void compute_tile(const char* lA, const char* lB, f32x4 (&acc)[F][F]) {
  const int lane = threadIdx.x & 63;
  const int wave = threadIdx.x >> 6;
  const int wr = wave >> 1, wc = wave & 1;
  const int kByte = (lane >> 4) * 16;
  const int rsel = lane & 15;
  bf16x8 a[F], b[F];
#pragma unroll
  for (int mi = 0; mi < F; ++mi) {
    int row = wr * (F * 16) + mi * 16 + rsel;
    a[mi] = *reinterpret_cast<const bf16x8*>(lA + row * 64 + kByte);
  }
#pragma unroll
  for (int ni = 0; ni < F; ++ni) {
    int row = wc * (F * 16) + ni * 16 + rsel;
    b[ni] = *reinterpret_cast<const bf16x8*>(lB + row * 64 + kByte);
  }
#pragma unroll
  for (int mi = 0; mi < F; ++mi)
#pragma unroll
    for (int ni = 0; ni < F; ++ni)
      acc[mi][ni] =
          __builtin_amdgcn_mfma_f32_16x16x32_bf16(a[mi], b[ni], acc[mi][ni], 0, 0, 0);
}

// ---------------- z GEMM (split-K): zpart[ks][m][r] = partial sums ----------------
template <int KS>
__global__ __launch_bounds__(256) void z_gemm_splitk(
    const unsigned short* __restrict__ xbf, const unsigned short* __restrict__ mbf,
    float* __restrict__ zpart) {
  int bid = blockIdx.x;
  int ksl = bid & (KS - 1);
  int rest = bid / KS;
  int nt = rest & 1, mt = rest >> 1;
  int row0 = mt * 64;
  int batch = row0 >> 11;
  int kbase = ksl * (DIN / KS);
  const char* xb = (const char*)(xbf + (size_t)row0 * DIN + kbase);
  const char* mb = (const char*)(mbf + ((size_t)batch * RANK + nt * 64) * DIN + kbase);
  __shared__ __align__(16) char lA[2][64 * 64];
  __shared__ __align__(16) char lB[2][64 * 64];
  f32x4 acc[2][2] = {};
  constexpr int NT = DIN / KS / 32;
  stage_tile<64>(xb, DIN * 2, lA[0]);
  stage_tile<64>(mb, DIN * 2, lB[0]);
  for (int t = 0; t < NT; ++t) {
    __syncthreads();
    if (t + 1 < NT) {
      stage_tile<64>(xb + (t + 1) * 64, DIN * 2, lA[(t + 1) & 1]);
      stage_tile<64>(mb + (t + 1) * 64, DIN * 2, lB[(t + 1) & 1]);
    }
    compute_tile<2>(lA[t & 1], lB[t & 1], acc);
  }
  const int lane = threadIdx.x & 63;
  const int wave = threadIdx.x >> 6;
  const int wr = wave >> 1, wc = wave & 1;
#pragma unroll
  for (int mi = 0; mi < 2; ++mi)
#pragma unroll
    for (int ni = 0; ni < 2; ++ni) {
      int c = nt * 64 + wc * 32 + ni * 16 + (lane & 15);
      int r0 = row0 + wr * 32 + mi * 16 + (lane >> 4) * 4;
#pragma unroll
      for (int j = 0; j < 4; ++j)
        zpart[((size_t)ksl * MTOT + r0 + j) * RANK + c] = acc[mi][ni][j];
    }
}

template <int KS>
__global__ void z_reduce_kernel(const float* __restrict__ zpart,
                                unsigned short* __restrict__ zbf) {
  const int n4 = MTOT * RANK / 4;
  int i = blockIdx.x * blockDim.x + threadIdx.x;
  if (i >= n4) return;
  float4 s = reinterpret_cast<const float4*>(zpart)[i];
#pragma unroll
  for (int k = 1; k < KS; ++k) {
    float4 v = reinterpret_cast<const float4*>(zpart)[(size_t)k * n4 + i];
    s.x += v.x; s.y += v.y; s.z += v.z; s.w += v.w;
  }
  ushort4 o;
  o.x = f2bf(s.x); o.y = f2bf(s.y); o.z = f2bf(s.z); o.w = f2bf(s.w);
  reinterpret_cast<ushort4*>(zbf)[i] = o;
}

// fallback (no split-K)
__global__ __launch_bounds__(256) void z_gemm_kernel(
    const unsigned short* __restrict__ xbf, const unsigned short* __restrict__ mbf,
    unsigned short* __restrict__ zbf) {
  int mt = blockIdx.x >> 1, nt = blockIdx.x & 1;
  int row0 = mt * 64;
  int batch = row0 >> 11;
  const char* xb = (const char*)(xbf + (size_t)row0 * DIN);
  const char* mb = (const char*)(mbf + ((size_t)batch * RANK + nt * 64) * DIN);
  __shared__ __align__(16) char lA[2][64 * 64];
  __shared__ __align__(16) char lB[2][64 * 64];
  f32x4 acc[2][2] = {};
  constexpr int NT = DIN / 32;
  stage_tile<64>(xb, DIN * 2, lA[0]);
  stage_tile<64>(mb, DIN * 2, lB[0]);
  for (int t = 0; t < NT; ++t) {
    __syncthreads();
    if (t + 1 < NT) {
      stage_tile<64>(xb + (t + 1) * 64, DIN * 2, lA[(t + 1) & 1]);
      stage_tile<64>(mb + (t + 1) * 64, DIN * 2, lB[(t + 1) & 1]);
    }
    compute_tile<2>(lA[t & 1], lB[t & 1], acc);
  }
  const int lane = threadIdx.x & 63;
  const int wave = threadIdx.x >> 6;
  const int wr = wave >> 1, wc = wave & 1;
#pragma unroll
  for (int mi = 0; mi < 2; ++mi)
#pragma unroll
    for (int ni = 0; ni < 2; ++ni) {
      int c = nt * 64 + wc * 32 + ni * 16 + (lane & 15);
      int r0 = row0 + wr * 32 + mi * 16 + (lane >> 4) * 4;
#pragma unroll
      for (int j = 0; j < 4; ++j)
        zbf[(size_t)(r0 + j) * RANK + c] = f2bf(acc[mi][ni][j]);
    }
}

// ---------------- main GEMM: 256x256, BK=64, 8 waves, 32x32x16 MFMA ----------------
// 8-phase pipelined loop, register prefetch one phase ahead.
// Phase P (0..7): buf = P>>2; q = P&3 = (kspair kp = q>>1, colfrag cf = q&1).
// Per phase: 8 x mfma_f32_32x32x16_bf16 (rf 0..3 x 2 kslots on acc[rf][cf]).
// Reads at P are for P+1: if next cf==0: 8 A-frags + 2 B-frags; else 2 B-frags.
// Stages: ph0 -> full tile t+1 into buf1 (8 loads); ph4 -> tile t+2 into buf0.
// vmcnt(0) at end of ph2 / ph6. Safety rule (verified per region): stage into
// region R at phase S requires last read-issue of R's old content <= S-2
// (read@S-2 completes before MFMA(S-1) < barrier(S-1) < stage(S)).
//   buf1 A last-read-issue ph5-prev, B ph6-prev -> stage ph0 OK.
//   buf0 A last-read-issue ph1,    B ph2      -> stage ph4 OK.

struct MainCtx {
  const char* aBase;  // lds + wr*16384 + (lane&31)*128
  const char* bBase;  // lds + 65536 + (wc>>1)*16384 + (wc&1)*8192 + (lane&31)*128
  int hi16;           // (lane>>5)*16
  int xorv;           // (lane&7)<<4
};

DEVI const bf16x8* lda32(const MainCtx& c, int d, int rf, int ks) {
  int col = (ks * 32 + c.hi16) ^ c.xorv;
  return reinterpret_cast<const bf16x8*>(c.aBase + d * 32768 + rf * 4096 + col);
}
DEVI const bf16x8* ldb32(const MainCtx& c, int d, int cf, int ks) {
  int col = (ks * 32 + c.hi16) ^ c.xorv;
  return reinterpret_cast<const bf16x8*>(c.bBase + d * 32768 + cf * 4096 + col);
}

template <int P>
struct PC {
  static constexpr int q = P & 3;
  static constexpr int kp = q >> 1, cf = q & 1;
  static constexpr int aCur = (P >> 1) & 1;
  static constexpr int bCur = P & 1;
  static constexpr int nP = (P + 1) & 7;
  static constexpr int nq = nP & 3;
  static constexpr int nbuf = nP >> 2;
  static constexpr int nkp = nq >> 1, ncf = nq & 1;
  static constexpr bool rdA = (ncf == 0);
  static constexpr int aNxt = (nP >> 1) & 1;
  static constexpr int bNxt = nP & 1;
};

template <int P, bool VM0, class STG>
DEVI void phase32(const MainCtx& c, f32x16 (&acc)[4][2], bf16x8 (&aS)[2][8],
                  bf16x8 (&bS)[2][2], STG&& stg) {
  using K = PC<P>;
  if constexpr (K::rdA) {
#pragma unroll
    for (int rf = 0; rf < 4; ++rf)
#pragma unroll
      for (int kk = 0; kk < 2; ++kk)
        aS[K::aNxt][rf * 2 + kk] = *lda32(c, K::nbuf, rf, K::nkp * 2 + kk);
  }
#pragma unroll
  for (int kk = 0; kk < 2; ++kk)
    bS[K::bNxt][kk] = *ldb32(c, K::nbuf, K::ncf, K::nkp * 2 + kk);
  stg();
  __builtin_amdgcn_s_setprio(1);
#pragma unroll
  for (int kk = 0; kk < 2; ++kk)
#pragma unroll
    for (int rf = 0; rf < 4; ++rf)
      acc[rf][K::cf] = __builtin_amdgcn_mfma_f32_32x32x16_bf16(
          aS[K::aCur][rf * 2 + kk], bS[K::bCur][kk], acc[rf][K::cf], 0, 0, 0);
  __builtin_amdgcn_s_setprio(0);
  if constexpr (VM0)
    asm volatile("s_waitcnt vmcnt(0)" ::: "memory");
  else
    asm volatile("" ::: "memory");
  __builtin_amdgcn_s_barrier();
}

__global__ __launch_bounds__(512, 2) void main_gemm_32(
    const unsigned short* __restrict__ xbf, const unsigned short* __restrict__ wlbf,
    const unsigned short* __restrict__ zbf, const unsigned short* __restrict__ wobf,
    const float* __restrict__ b_lin, float* __restrict__ out) {
  __shared__ __align__(16) char lds[131072];

  const int tid = threadIdx.x;
  const int lane = tid & 63, wave = tid >> 6;
  const int wr = wave >> 2, wc = wave & 3;

  int bid = blockIdx.x;                   // 512 blocks, 512%8==0
  int swz = (bid & 7) * 64 + (bid >> 3);  // bijective XCD swizzle
  int mt = swz >> 4, nt = swz & 15;
  const int row0 = mt * 256, col0 = nt * 256;

  const char* xb = (const char*)(xbf + (size_t)row0 * DIN);
  const char* wb = (const char*)(wlbf + (size_t)col0 * DIN);
  const char* zb = (const char*)(zbf + (size_t)row0 * RANK);
  const char* ob = (const char*)(wobf + (size_t)col0 * RANK);

  // staging lane constants (pre-swizzled source; linear LDS dest — rule 21)
  const int srow8 = lane >> 3;
  const int scolS = ((lane & 7) ^ srow8) << 4;
  const int chunk0 = wave * 2;

  auto stage = [&](const char* gbase, int ld, int ldsOff) {
    gload16(gbase + (size_t)(chunk0 * 8 + srow8) * ld + scolS,
            (void*)&lds[ldsOff + chunk0 * 1024]);
    gload16(gbase + (size_t)(chunk0 * 8 + 8 + srow8) * ld + scolS,
            (void*)&lds[ldsOff + chunk0 * 1024 + 1024]);
  };
  auto stageA = [&](int k, int h, int d) {
    const char* g; int ld;
    if (k < 64) { g = xb + (size_t)h * 128 * (DIN * 2) + (size_t)k * 128; ld = DIN * 2; }
    else        { g = zb + (size_t)h * 128 * (RANK * 2) + (size_t)(k - 64) * 128; ld = RANK * 2; }
    stage(g, ld, d * 32768 + h * 16384);
  };
  auto stageB = [&](int k, int h, int d) {
    const char* g; int ld;
    if (k < 64) { g = wb + (size_t)h * 128 * (DIN * 2) + (size_t)k * 128; ld = DIN * 2; }
    else        { g = ob + (size_t)h * 128 * (RANK * 2) + (size_t)(k - 64) * 128; ld = RANK * 2; }
    stage(g, ld, 65536 + d * 32768 + h * 16384);
  };

  MainCtx c{lds + wr * 16384 + (lane & 31) * 128,
            lds + 65536 + (wc >> 1) * 16384 + (wc & 1) * 8192 + (lane & 31) * 128,
            (lane >> 5) * 16, (lane & 7) << 4};

  f32x16 acc[4][2] = {};
  bf16x8 aS[2][8], bS[2][2];

  // prologue: tile0 -> buf0 (8 loads), drain, read ph0 fragments
  stageA(0, 0, 0); stageA(0, 1, 0);
  stageB(0, 0, 0); stageB(0, 1, 0);
  asm volatile("s_waitcnt vmcnt(0)" ::: "memory");
  __builtin_amdgcn_s_barrier();
#pragma unroll
  for (int rf = 0; rf < 4; ++rf)
#pragma unroll
    for (int kk = 0; kk < 2; ++kk)
      aS[0][rf * 2 + kk] = *lda32(c, 0, rf, kk);
#pragma unroll
  for (int kk = 0; kk < 2; ++kk) bS[0][kk] = *ldb32(c, 0, 0, kk);

  constexpr int NKT = 66;  // 64 (x/wl) + 2 (z/wo)
  for (int j = 0; j < NKT / 2; ++j) {
    int t = 2 * j;
    int k1 = (t + 1 < NKT - 1) ? t + 1 : NKT - 1;
    int k2 = (t + 2 < NKT - 1) ? t + 2 : NKT - 1;
    phase32<0, false>(c, acc, aS, bS, [&] {
      stageA(k1, 0, 1); stageA(k1, 1, 1); stageB(k1, 0, 1); stageB(k1, 1, 1);
    });
    phase32<1, false>(c, acc, aS, bS, [&] {});
    phase32<2, true >(c, acc, aS, bS, [&] {});
    phase32<3, false>(c, acc, aS, bS, [&] {});
    phase32<4, false>(c, acc, aS, bS, [&] {
      stageA(k2, 0, 0); stageA(k2, 1, 0); stageB(k2, 0, 0); stageB(k2, 1, 0);
    });
    phase32<5, false>(c, acc, aS, bS, [&] {});
    phase32<6, true >(c, acc, aS, bS, [&] {});
    phase32<7, false>(c, acc, aS, bS, [&] {});
  }
  asm volatile("s_waitcnt vmcnt(0)" ::: "memory");

  // epilogue — 32x32 C/D layout: col=lane&31, row=(reg&3)+8*(reg>>2)+4*(lane>>5)
  const int rbase0 = row0 + wr * 128 + (lane >> 5) * 4;
  const int cbase0 = col0 + wc * 64 + (lane & 31);
#pragma unroll
  for (int rf = 0; rf < 4; ++rf)
#pragma unroll
    for (int cf = 0; cf < 2; ++cf) {
      int cc = cbase0 + cf * 32;
      float bv = b_lin[cc];
      int rb = rbase0 + rf * 32;
#pragma unroll
      for (int reg = 0; reg < 16; ++reg) {
        int r = rb + (reg & 3) + 8 * (reg >> 2);
        out[(size_t)r * DOUT + cc] = acc[rf][cf][reg] + bv;
      }
    }
}

// ---------------- launch ----------------

extern "C" void kernel_launch(void* const* d_in, const int* in_sizes, int n_in,
                              void* d_out, int out_size, void* d_ws, size_t ws_size,
                              hipStream_t stream) {
  const float* x = (const float*)d_in[0];
  const float* log_lr = (const float*)d_in[1];
  const float* state = (const float*)d_in[2];
  const float* w_bsp = (const float*)d_in[4];
  const float* w_out = (const float*)d_in[5];
  const float* w_lin = (const float*)d_in[6];
  const float* b_lin = (const float*)d_in[7];
  float* out = (float*)d_out;

  unsigned short* xbf = (unsigned short*)d_ws;              // 67108864 B
  unsigned short* wlbf = xbf + (size_t)MTOT * DIN;          // 33554432 B
  unsigned short* wobf = wlbf + (size_t)DOUT * DIN;         // 1048576 B
  unsigned short* mbf = wobf + (size_t)DOUT * RANK;         // 4194304 B
  unsigned short* zbf = mbf + (size_t)BS * RANK * DIN;      // 2097152 B
  float* zpart = (float*)(zbf + (size_t)MTOT * RANK);       // 16777216 B
  const size_t need_split = 108003328 + 16777216;

  prep_all_kernel<<<2048, 256, 0, stream>>>(x, w_lin, w_out, log_lr, state, w_bsp,
                                            xbf, wlbf, wobf, mbf);

  if (ws_size >= need_split) {
    z_gemm_splitk<4><<<1024, 256, 0, stream>>>(xbf, mbf, zpart);
    z_reduce_kernel<4><<<1024, 256, 0, stream>>>(zpart, zbf);
  } else {
    z_gemm_kernel<<<256, 256, 0, stream>>>(xbf, mbf, zbf);
  }

  main_gemm_32<<<512, 512, 0, stream>>>(xbf, wlbf, zbf, wobf, b_lin, out);
}